// Round 1
// 191.234 us; speedup vs baseline: 1.0144x; 1.0144x over previous
//
#include <hip/hip_runtime.h>

#define NN 50000
#define DD 128
#define SLOPE 0.01f
#define NB 782        // buckets of 64 nodes: bucket = v>>6
#define BCAP 2560     // per-bucket cap; mean 2046, sigma 45 -> +11 sigma
#define ECH 6144      // edges per bin block
#define BST 512       // convert_bin block threads
#define PB 2          // buckets per thread in prefix scan (512*2 >= 782)
#define OVCAP 8192
#define HP 136        // Hs row pitch (bf16): 272B rows -> even b128 bank groups

using bf16x8 = __attribute__((ext_vector_type(8))) short;
using f32x4  = __attribute__((ext_vector_type(4))) float;

// ---------------- bf16 helpers (RNE) ----------------
__device__ inline float bflo(unsigned int w) { return __uint_as_float(w << 16); }
__device__ inline float bfhi(unsigned int w) { return __uint_as_float(w & 0xffff0000u); }
__device__ inline float sbf(short s) {
    return __uint_as_float(((unsigned int)(unsigned short)s) << 16);
}
__device__ inline unsigned int rnebf(float f) {
    unsigned int u = __float_as_uint(f);
    return (u + 0x7fffu + ((u >> 16) & 1u)) >> 16;
}
__device__ inline unsigned int pack2(float lo, float hi) {
    return rnebf(lo) | (rnebf(hi) << 16);
}
__device__ inline uint4 pack8f(const float* f) {
    uint4 o;
    o.x = pack2(f[0], f[1]); o.y = pack2(f[2], f[3]);
    o.z = pack2(f[4], f[5]); o.w = pack2(f[6], f[7]);
    return o;
}
__device__ inline void addrow(float* acc, uint4 r) {
    acc[0] += bflo(r.x); acc[1] += bfhi(r.x);
    acc[2] += bflo(r.y); acc[3] += bfhi(r.y);
    acc[4] += bflo(r.z); acc[5] += bfhi(r.z);
    acc[6] += bflo(r.w); acc[7] += bfhi(r.w);
}

// ---------------------------------------------------------------------------
// Fused: blocks [0,nbin) do LDS counting-sort binning of ECH edges each;
// blocks [nbin,..) convert E/W1/W2 fp32->bf16. Independent work co-scheduled.
// Record layout in srt/stag: u (bits 0..15) | v&63 (bits 16..21) | bucket
// (bits 22..31).  16+6+10 = 32 bits exactly (NB=782 < 1024).
// ---------------------------------------------------------------------------
__global__ __launch_bounds__(BST) void convert_bin(
    const float* __restrict__ E, const float* __restrict__ W1,
    const float* __restrict__ W2, const int* __restrict__ src,
    const int* __restrict__ dst, unsigned short* __restrict__ Ebf,
    unsigned short* __restrict__ W1b, unsigned short* __restrict__ W2b,
    int* __restrict__ gtail, unsigned int* __restrict__ stag,
    int* __restrict__ ovf_cnt, int2* __restrict__ ovf,
    int n_edges, int nbin)
{
    const int tid = threadIdx.x;

    if (blockIdx.x >= nbin) {
        // ---------------- convert branch ----------------
        const int NE8 = NN * DD / 8;      // 800000
        const int NW8 = DD * DD / 8;      // 2048
        int t = (blockIdx.x - nbin) * BST + tid;
        const float* s; unsigned short* d; int idx;
        if (t < NE8)                { s = E;  d = Ebf; idx = t; }
        else if (t < NE8 + NW8)     { s = W1; d = W1b; idx = t - NE8; }
        else if (t < NE8 + 2 * NW8) { s = W2; d = W2b; idx = t - NE8 - NW8; }
        else return;
        float4 a = ((const float4*)s)[(size_t)idx * 2];
        float4 b = ((const float4*)s)[(size_t)idx * 2 + 1];
        uint4 o;
        o.x = pack2(a.x, a.y); o.y = pack2(a.z, a.w);
        o.z = pack2(b.x, b.y); o.w = pack2(b.z, b.w);
        ((uint4*)d)[idx] = o;
        return;
    }

    // ---------------- bin branch: LDS counting sort by bucket ----------------
    __shared__ unsigned int srt[ECH];     // 24 KB
    __shared__ int cnt[NB], off[NB], pos[NB], gbase[NB];
    __shared__ int wsum[BST / 64];

    const int e0 = blockIdx.x * ECH;
    const int m = min(ECH, n_edges - e0);

    for (int b = tid; b < NB; b += BST) cnt[b] = 0;
    __syncthreads();

    for (int i = tid; i < m; i += BST)
        atomicAdd(&cnt[dst[e0 + i] >> 6], 1);
    __syncthreads();

    const int lane = tid & 63, w = tid >> 6;
    int b0 = tid * PB;
    int loc[PB]; int s = 0;
    #pragma unroll
    for (int j = 0; j < PB; ++j) {
        int bb = b0 + j;
        int cv = (bb < NB) ? cnt[bb] : 0;
        loc[j] = s; s += cv;
    }
    int incl = s;
    #pragma unroll
    for (int d = 1; d < 64; d <<= 1) {
        int t2 = __shfl_up(incl, d);
        if (lane >= d) incl += t2;
    }
    if (lane == 63) wsum[w] = incl;
    __syncthreads();
    int wbase = 0;
    for (int w2 = 0; w2 < w; ++w2) wbase += wsum[w2];
    int base = wbase + incl - s;
    #pragma unroll
    for (int j = 0; j < PB; ++j) {
        int bb = b0 + j;
        if (bb < NB) { off[bb] = base + loc[j]; pos[bb] = base + loc[j]; }
    }
    __syncthreads();

    for (int i = tid; i < m; i += BST) {
        int v = dst[e0 + i];
        int u = src[e0 + i];
        int bb = v >> 6;
        int p = atomicAdd(&pos[bb], 1);
        srt[p] = (unsigned int)u | ((unsigned int)(v & 63) << 16)
               | ((unsigned int)bb << 22);
    }
    __syncthreads();

    // flush step 1: one global atomic per nonempty bucket reserves space
    for (int bb = tid; bb < NB; bb += BST) {
        int c = cnt[bb];
        if (c) gbase[bb] = atomicAdd(&gtail[bb], c);
    }
    __syncthreads();

    // flush step 2: all threads stream records out in parallel.
    // Consecutive i within a bucket run -> consecutive stag addresses.
    for (int i = tid; i < m; i += BST) {
        unsigned int r = srt[i];
        int bb = (int)(r >> 22);
        int gp = gbase[bb] + (i - off[bb]);
        if (gp < BCAP) {
            stag[(size_t)bb * BCAP + gp] = r & 0x3fffffu;
        } else {
            int oi = atomicAdd(ovf_cnt, 1);
            if (oi < OVCAP)
                ovf[oi] = make_int2((int)(r & 0xffffu),
                                    bb * 64 + (int)((r >> 16) & 63));
        }
    }
}

// ---------------------------------------------------------------------------
// Fused gather + GEMM. One block of 512 threads (8 waves) per bucket (64
// nodes).  Occupancy rationale: grid = 782 blocks = 3.05 blocks/CU is the
// binding limit at 256 threads (measured OccupancyPercent 27.8 -> latency-
// bound gather).  8 waves/block doubles resident waves to ~24/CU.
//   A) counting-sort the bucket's records by node-low6 in LDS
//   B) gather-sum E rows per node (8-deep load pipeline), 32 nodes per pass
//      x 2 passes, fold any overflow edges, store H rows bf16 in LDS
//   C) 8 waves: wave w does rows (w>>1)*16.., column half (w&1) of the
//      16x16x32-MFMA GEMM; fused leaky epilogue.
// ---------------------------------------------------------------------------
__global__ __launch_bounds__(512) void bucket_fused(
    const unsigned short* __restrict__ Ebf, const int* __restrict__ gtail,
    const unsigned int* __restrict__ stag, const int* __restrict__ ovf_cnt,
    const int2* __restrict__ ovf,
    const unsigned short* __restrict__ W1b, const unsigned short* __restrict__ W2b,
    const float* __restrict__ b1, const float* __restrict__ b2,
    float* __restrict__ out)
{
    __shared__ unsigned short sorted[BCAP];       // 5 KB
    __shared__ unsigned short Hs[64][HP];         // 17 KB
    __shared__ int cnt[64], off[65], pos[64];
    __shared__ int s_novf;

    const int b = blockIdx.x;
    const int tid = threadIdx.x;
    int len = gtail[b]; len = len < BCAP ? len : BCAP;
    const unsigned int* seg = stag + (size_t)b * BCAP;

    if (tid == 0) { int t = *ovf_cnt; s_novf = t < OVCAP ? t : OVCAP; }
    if (tid < 64) cnt[tid] = 0;
    __syncthreads();
    for (int i = tid; i < len; i += 512)
        atomicAdd(&cnt[(seg[i] >> 16) & 63], 1);
    __syncthreads();
    if (tid == 0) {
        int a = 0;
        for (int j = 0; j < 64; ++j) { off[j] = a; pos[j] = a; a += cnt[j]; }
        off[64] = a;
    }
    __syncthreads();
    for (int i = tid; i < len; i += 512) {
        unsigned int r = seg[i];
        int p = atomicAdd(&pos[(r >> 16) & 63], 1);
        sorted[p] = (unsigned short)(r & 0xffffu);
    }
    __syncthreads();
    const int novf = s_novf;

    // ---- gather: 16 lanes per node x 32 nodes per pass, 2 passes ----
    const int g = tid >> 4;           // 0..31
    const int c = tid & 15;
    const uint4* E4 = (const uint4*)Ebf;
    for (int p2 = 0; p2 < 2; ++p2) {
        int nl = p2 * 32 + g;
        int v = b * 64 + nl;
        if (v >= NN) continue;
        float acc[8] = {};
        int i = off[nl], e1 = off[nl + 1];
        for (; i + 8 <= e1; i += 8) {
            uint4 r0 = E4[(size_t)sorted[i]     * 16 + c];
            uint4 r1 = E4[(size_t)sorted[i + 1] * 16 + c];
            uint4 r2 = E4[(size_t)sorted[i + 2] * 16 + c];
            uint4 r3 = E4[(size_t)sorted[i + 3] * 16 + c];
            uint4 r4 = E4[(size_t)sorted[i + 4] * 16 + c];
            uint4 r5 = E4[(size_t)sorted[i + 5] * 16 + c];
            uint4 r6 = E4[(size_t)sorted[i + 6] * 16 + c];
            uint4 r7 = E4[(size_t)sorted[i + 7] * 16 + c];
            addrow(acc, r0); addrow(acc, r1); addrow(acc, r2); addrow(acc, r3);
            addrow(acc, r4); addrow(acc, r5); addrow(acc, r6); addrow(acc, r7);
        }
        for (; i + 2 <= e1; i += 2) {
            uint4 r0 = E4[(size_t)sorted[i]     * 16 + c];
            uint4 r1 = E4[(size_t)sorted[i + 1] * 16 + c];
            addrow(acc, r0); addrow(acc, r1);
        }
        if (i < e1) addrow(acc, E4[(size_t)sorted[i] * 16 + c]);

        if (novf > 0) {                    // rare path: fold overflow edges
            for (int k = 0; k < novf; ++k) {
                int2 e = ovf[k];
                if (e.y == v) addrow(acc, E4[(size_t)e.x * 16 + c]);
            }
        }
        *(uint4*)&Hs[nl][c * 8] = pack8f(acc);
    }
    __syncthreads();

    // ---- GEMM: wave w -> rows (w>>1)*16 .. +15, col half (w&1) ----
    const int wave = tid >> 6;
    const int lane = tid & 63;
    const int rw = wave >> 1;         // row-quarter 0..3
    const int ch = wave & 1;          // column half 0..1
    const int v0 = b * 64 + rw * 16;
    if (v0 >= NN) return;             // only trailing waves of last bucket
    const int m = lane & 15;
    const int quad = lane >> 4;

    bf16x8 aH[4], aE[4];
    const unsigned short* hrow = &Hs[rw * 16 + m][quad * 8];
    const unsigned short* erow = Ebf + (size_t)(v0 + m) * DD + quad * 8;
    #pragma unroll
    for (int ks = 0; ks < 4; ++ks) {
        bf16x8 h8 = *(const bf16x8*)(hrow + ks * 32);
        bf16x8 e8 = *(const bf16x8*)(erow + ks * 32);
        aH[ks] = h8;
        bf16x8 eh;
        #pragma unroll
        for (int j = 0; j < 8; ++j)
            eh[j] = (short)rnebf(sbf(h8[j]) * sbf(e8[j]));
        aE[ks] = eh;
    }

    #pragma unroll
    for (int jt = ch * 4; jt < ch * 4 + 4; ++jt) {
        const int j0 = jt * 16;
        const unsigned short* w1r = W1b + (size_t)(j0 + m) * DD + quad * 8;
        const unsigned short* w2r = W2b + (size_t)(j0 + m) * DD + quad * 8;
        f32x4 acc1 = {0.f, 0.f, 0.f, 0.f}, acc2 = {0.f, 0.f, 0.f, 0.f};
        #pragma unroll
        for (int ks = 0; ks < 4; ++ks) {
            bf16x8 bw1 = *(const bf16x8*)(w1r + ks * 32);
            bf16x8 bw2 = *(const bf16x8*)(w2r + ks * 32);
            acc1 = __builtin_amdgcn_mfma_f32_16x16x32_bf16(aH[ks], bw1, acc1, 0, 0, 0);
            acc2 = __builtin_amdgcn_mfma_f32_16x16x32_bf16(aE[ks], bw2, acc2, 0, 0, 0);
        }
        const float bb1 = b1[j0 + m], bb2 = b2[j0 + m];
        #pragma unroll
        for (int i = 0; i < 4; ++i) {
            int row = v0 + quad * 4 + i;
            if (row < NN) {
                float x1 = acc1[i] + bb1; x1 = x1 > 0.f ? x1 : SLOPE * x1;
                float x2 = acc2[i] + bb2; x2 = x2 > 0.f ? x2 : SLOPE * x2;
                out[(size_t)row * DD + j0 + m] = x1 + x2;
            }
        }
    }
}

// ============== minimal fallback (ws too small): fp32 atomics ==============
__global__ __launch_bounds__(256) void scatter_add(
    const float* __restrict__ E, const int* __restrict__ src,
    const int* __restrict__ dst, float* __restrict__ H, int n_edges)
{
    int t = blockIdx.x * 256 + threadIdx.x;
    int e = t >> 5;
    if (e >= n_edges) return;
    int c = t & 31;
    float4 a = ((const float4*)E)[(size_t)src[e] * 32 + c];
    float* hp = H + (size_t)dst[e] * DD + c * 4;
    atomicAdd(hp + 0, a.x); atomicAdd(hp + 1, a.y);
    atomicAdd(hp + 2, a.z); atomicAdd(hp + 3, a.w);
}

__global__ __launch_bounds__(256) void fused_mlp(
    const float* __restrict__ E, const float* __restrict__ H,
    const float* __restrict__ W1, const float* __restrict__ b1,
    const float* __restrict__ W2, const float* __restrict__ b2,
    float* __restrict__ out)
{
    __shared__ float Hsf[32][DD];
    __shared__ float EHs[32][DD];
    __shared__ float W1s[DD][20];
    __shared__ float W2s[DD][20];
    const int tid = threadIdx.x;
    const int v0 = blockIdx.x * 32;
    const int nvalid = min(32, NN - v0);
    for (int i = 0; i < 4; ++i) {
        int f = tid + 256 * i;
        int n = f >> 5, c = f & 31;
        float4 h = make_float4(0.f, 0.f, 0.f, 0.f);
        float4 eh = h;
        if (n < nvalid) {
            h = ((const float4*)H)[(size_t)(v0 + n) * 32 + c];
            float4 e4 = ((const float4*)E)[(size_t)(v0 + n) * 32 + c];
            eh = make_float4(e4.x * h.x, e4.y * h.y, e4.z * h.z, e4.w * h.w);
        }
        *((float4*)&Hsf[n][c * 4]) = h;
        *((float4*)&EHs[n][c * 4]) = eh;
    }
    const int jg = tid & 63;
    const int n0 = (tid >> 6) * 8;
    float acc1a[8] = {}, acc1b[8] = {}, acc2a[8] = {}, acc2b[8] = {};
    for (int t8 = 0; t8 < 8; ++t8) {
        const int k0 = t8 * 16;
        __syncthreads();
        for (int i = 0; i < 8; ++i) {
            int f = tid + 256 * i;
            int j = f >> 4, kk = f & 15;
            W1s[j][kk] = W1[j * DD + k0 + kk];
            W2s[j][kk] = W2[j * DD + k0 + kk];
        }
        __syncthreads();
        for (int c = 0; c < 4; ++c) {
            float4 w1a = *((const float4*)&W1s[jg][c * 4]);
            float4 w1b = *((const float4*)&W1s[jg + 64][c * 4]);
            float4 w2a = *((const float4*)&W2s[jg][c * 4]);
            float4 w2b = *((const float4*)&W2s[jg + 64][c * 4]);
            const int kk = k0 + c * 4;
            for (int n = 0; n < 8; ++n) {
                float4 h = *((const float4*)&Hsf[n0 + n][kk]);
                float4 eh = *((const float4*)&EHs[n0 + n][kk]);
                acc1a[n] += h.x * w1a.x + h.y * w1a.y + h.z * w1a.z + h.w * w1a.w;
                acc1b[n] += h.x * w1b.x + h.y * w1b.y + h.z * w1b.z + h.w * w1b.w;
                acc2a[n] += eh.x * w2a.x + eh.y * w2a.y + eh.z * w2a.z + eh.w * w2a.w;
                acc2b[n] += eh.x * w2b.x + eh.y * w2b.y + eh.z * w2b.z + eh.w * w2b.w;
            }
        }
    }
    const float b1a = b1[jg], b1b = b1[jg + 64];
    const float b2a = b2[jg], b2b = b2[jg + 64];
    for (int n = 0; n < 8; ++n) {
        if (n0 + n < nvalid) {
            const int v = v0 + n0 + n;
            float x1 = acc1a[n] + b1a; x1 = x1 > 0.f ? x1 : SLOPE * x1;
            float x2 = acc2a[n] + b2a; x2 = x2 > 0.f ? x2 : SLOPE * x2;
            out[(size_t)v * DD + jg] = x1 + x2;
            float y1 = acc1b[n] + b1b; y1 = y1 > 0.f ? y1 : SLOPE * y1;
            float y2 = acc2b[n] + b2b; y2 = y2 > 0.f ? y2 : SLOPE * y2;
            out[(size_t)v * DD + jg + 64] = y1 + y2;
        }
    }
}
// ===========================================================================

extern "C" void kernel_launch(void* const* d_in, const int* in_sizes, int n_in,
                              void* d_out, int out_size, void* d_ws, size_t ws_size,
                              hipStream_t stream)
{
    const float* E  = (const float*)d_in[0];
    const float* W1 = (const float*)d_in[1];
    const float* b1 = (const float*)d_in[2];
    const float* W2 = (const float*)d_in[3];
    const float* b2 = (const float*)d_in[4];
    const int* src  = (const int*)d_in[5];
    const int* dst  = (const int*)d_in[6];
    float* out = (float*)d_out;
    const int n_edges = in_sizes[5];

    char* ws = (char*)d_ws;
    auto al = [](size_t x) { return (x + 255) & ~(size_t)255; };

    const size_t off_tail = 0;                                  // NB*4
    const size_t off_ovfc = (size_t)NB * 4;
    const size_t off_ovf  = al(off_ovfc + 4);
    const size_t off_stag = al(off_ovf + (size_t)OVCAP * 8);
    const size_t off_Ebf  = al(off_stag + (size_t)NB * BCAP * 4);
    const size_t off_W1b  = al(off_Ebf + (size_t)NN * DD * 2);
    const size_t off_W2b  = al(off_W1b + (size_t)DD * DD * 2);
    const size_t need_bf  = off_W2b + (size_t)DD * DD * 2;      // ~21 MB

    if (ws_size >= need_bf) {
        int*  gtail   = (int*)(ws + off_tail);
        int*  ovf_cnt = (int*)(ws + off_ovfc);
        int2* ovf     = (int2*)(ws + off_ovf);
        unsigned int*   stag = (unsigned int*)(ws + off_stag);
        unsigned short* Ebf  = (unsigned short*)(ws + off_Ebf);
        unsigned short* W1b  = (unsigned short*)(ws + off_W1b);
        unsigned short* W2b  = (unsigned short*)(ws + off_W2b);

        const int nbin = (n_edges + ECH - 1) / ECH;
        const int ncv  = NN * DD / 8 + 2 * (DD * DD / 8);
        const int ncvb = (ncv + BST - 1) / BST;

        hipMemsetAsync(ws, 0, off_ovf, stream);   // gtail + ovf_cnt
        convert_bin<<<nbin + ncvb, BST, 0, stream>>>(
            E, W1, W2, src, dst, Ebf, W1b, W2b,
            gtail, stag, ovf_cnt, ovf, n_edges, nbin);
        bucket_fused<<<NB, 512, 0, stream>>>(
            Ebf, gtail, stag, ovf_cnt, ovf, W1b, W2b, b1, b2, out);
        return;
    }

    // fallback: fp32 atomics into H (= ws if it fits, else out), then fused MLP
    const size_t hbytes = (size_t)NN * DD * sizeof(float);
    float* H = (ws_size >= hbytes) ? (float*)ws : out;
    hipMemsetAsync(H, 0, hbytes, stream);
    scatter_add<<<((n_edges * 32) + 255) / 256, 256, 0, stream>>>(
        E, src, dst, H, n_edges);
    fused_mlp<<<(NN + 31) / 32, 256, 0, stream>>>(E, H, W1, b1, W2, b2, out);
}